// Round 9
// baseline (195.738 us; speedup 1.0000x reference)
//
#include <hip/hip_runtime.h>

#define HW     3136      // 56*56
#define WIDTH  56
#define C      256
#define CR     64
#define NT     64
#define TT     8
#define PW     64        // padded row width (bf16 y)
#define PH     58        // padded rows
#define YPLANE (PH*PW)   // 3712 shorts per (nt,ch) plane
#define YBYTES ((size_t)NT * CR * YPLANE * 2)        // 30,408,704
#define CVBYTES ((size_t)NT * 9 * HW * 4)            // 7,225,344

#define BN_INV 0.9999950000374997f   // 1/sqrt(1+1e-5)

typedef __attribute__((ext_vector_type(8))) short short8;
typedef __attribute__((ext_vector_type(8))) unsigned short ushort8;
typedef __attribute__((ext_vector_type(4))) float f32x4;
typedef __attribute__((ext_vector_type(2))) float f32x2;

static __device__ __forceinline__ float relu(float v) { return fmaxf(v, 0.0f); }
static __device__ __forceinline__ float bf2f(unsigned short u) {
    return __builtin_bit_cast(float, (unsigned)u << 16);
}
static __device__ __forceinline__ unsigned short f2bf(float f) {
    unsigned u = __builtin_bit_cast(unsigned, f);
    unsigned r = (u + 0x7FFFu + ((u >> 16) & 1u)) >> 16;   // RNE
    return (unsigned short)r;
}
static __device__ __forceinline__ unsigned pack2(float a, float b) {
    return (unsigned)f2bf(a) | ((unsigned)f2bf(b) << 16);
}

// k0: conv21_w fp32 [64][256] -> bf16 (k-contiguous rows for A-fragments)
__global__ __launch_bounds__(256) void k0_cvt_w(const float* __restrict__ w,
                                                unsigned short* __restrict__ wbf) {
    int i = blockIdx.x * 256 + threadIdx.x;   // 0..16383
    wbf[i] = f2bf(w[i]);
}

// zero the halo cells of all 64 planes of frame nt (rows 0,57; col 0; cols 57..63)
static __device__ __forceinline__ void halo_zero(int nt, int tid,
                                                 unsigned short* __restrict__ y) {
    const int ch = tid >> 2, part = tid & 3;
    unsigned short* pl = y + ((size_t)nt * CR + ch) * YPLANE;
    if (part == 0) {
        ushort8 z = (ushort8)0;
#pragma unroll
        for (int j = 0; j < 8; ++j) *(ushort8*)(pl + j * 8) = z;          // row 0
    } else if (part == 1) {
        ushort8 z = (ushort8)0;
        unsigned short* q = pl + 57 * PW;                                  // row 57
#pragma unroll
        for (int j = 0; j < 8; ++j) *(ushort8*)(q + j * 8) = z;
    } else if (part == 2) {
        for (int r = 1; r <= 28; ++r) {
            unsigned short* q = pl + r * PW + 57;
#pragma unroll
            for (int j = 0; j < 8; ++j) q[j] = 0;
        }
    } else {
        for (int r = 29; r <= 56; ++r) {
            unsigned short* q = pl + r * PW + 57;
#pragma unroll
            for (int j = 0; j < 8; ++j) q[j] = 0;
        }
        pl[PW] = 0;                                                        // row 1 col 0
    }
}

// k1: y = relu(bn21(conv21(x))) via MFMA, bf16 padded output.
// Block = TP-pixel tile of one frame. Collaborative staging: thread loads 8x
// float4 (1KB/wave-instr) of a 32-ch K-slice into dbuf LDS (px-major, oct-XOR
// swizzle). A-fragments stream from global wbf (32KB, L2-hot) into registers.
// One barrier per K-step. LDS 35KB -> 3 blocks/CU.
template<int TP>
__global__ __launch_bounds__(256) void k1_mfma(const float* __restrict__ x,
                                               const unsigned short* __restrict__ wbf,
                                               const float* __restrict__ g,
                                               const float* __restrict__ bb,
                                               unsigned short* __restrict__ y) {
    constexpr int NB = TP / 64;          // n-tiles per wave (4 or 1)
    constexpr int NQ = TP / 4;           // px-quads per tile (64 or 16)
    __shared__ unsigned short Bl[2][NQ][136];   // [buf][px-quad][4 sub x 32 + 8 pad]

    const int tid  = threadIdx.x;
    const int lane = tid & 63;
    const int wv   = tid >> 6;

    int nt, px0;
    if (TP == 256) {
        if (blockIdx.x >= 768) { halo_zero(blockIdx.x - 768, tid, y); return; }
        nt = blockIdx.x / 12; px0 = (blockIdx.x % 12) * 256;
    } else {
        nt = blockIdx.x; px0 = 3072;
    }

    const int p4 = tid & (NQ - 1);       // px-quad
    const int c8 = tid / NQ;             // ch-oct (0..3 valid)
    const bool active = (TP == 256) ? true : (c8 < 4);

    const float* xbase = x + (size_t)nt * (C * HW) + px0 + 4 * p4;
    const int frow = lane & 15;
    const int hi   = lane >> 4;
    const unsigned short* abase = wbf + frow * C + hi * 8;

    f32x4 acc[NB][4];
#pragma unroll
    for (int nb = 0; nb < NB; ++nb)
#pragma unroll
        for (int mb = 0; mb < 4; ++mb) acc[nb][mb] = (f32x4)0.0f;

    f32x4  xq[8];
    short8 afr[2][4];

#define LOADB(KS)                                                          \
    if (active) {                                                          \
        const float* _p = xbase + (size_t)((KS) * 32 + c8 * 8) * HW;       \
        _Pragma("unroll")                                                  \
        for (int j = 0; j < 8; ++j) xq[j] = *(const f32x4*)(_p + (size_t)j * HW); \
    }

#define LOADA(KS, DST)                                                     \
    _Pragma("unroll")                                                      \
    for (int mb = 0; mb < 4; ++mb)                                         \
        (DST)[mb] = *(const short8*)(abase + mb * 16 * C + (KS) * 32);

#define WRITEB(BUF)                                                        \
    if (active) {                                                          \
        _Pragma("unroll")                                                  \
        for (int i = 0; i < 4; ++i) {                                      \
            union { unsigned d[4]; short8 v; } pk;                         \
            pk.d[0] = pack2(xq[0][i], xq[1][i]);                           \
            pk.d[1] = pack2(xq[2][i], xq[3][i]);                           \
            pk.d[2] = pack2(xq[4][i], xq[5][i]);                           \
            pk.d[3] = pack2(xq[6][i], xq[7][i]);                           \
            *(short8*)&Bl[BUF][p4][i * 32 + ((c8 ^ i) & 3) * 8] = pk.v;    \
        }                                                                  \
    }

    LOADB(0)
    LOADA(0, afr[0])
    WRITEB(0)
    __syncthreads();

#pragma unroll
    for (int ks = 0; ks < 8; ++ks) {
        const int cb = ks & 1;
        if (ks < 7) {
            LOADB(ks + 1)              // issue next global loads early
            LOADA(ks + 1, afr[cb ^ 1])
        }
        short8 bfrag[NB];
#pragma unroll
        for (int nb = 0; nb < NB; ++nb) {
            const int pxl = wv * (TP / 4) + nb * 16 + frow;
            bfrag[nb] = *(const short8*)
                &Bl[cb][pxl >> 2][(pxl & 3) * 32 + ((hi ^ (pxl & 3)) & 3) * 8];
        }
#pragma unroll
        for (int nb = 0; nb < NB; ++nb)
#pragma unroll
            for (int mb = 0; mb < 4; ++mb)
                acc[nb][mb] = __builtin_amdgcn_mfma_f32_16x16x32_bf16(
                    afr[cb][mb], bfrag[nb], acc[nb][mb], 0, 0, 0);
        if (ks < 7) {
            WRITEB(cb ^ 1)
            __syncthreads();
        }
    }
#undef LOADB
#undef LOADA
#undef WRITEB

    // epilogue: D col = lane&15 (pixel), row = hi*4 + rr (output o); bf16 store
    unsigned short* ybase = y + (size_t)nt * CR * YPLANE;
#pragma unroll
    for (int nb = 0; nb < NB; ++nb) {
        const int p = px0 + wv * (TP / 4) + nb * 16 + frow;
        const int r = p / WIDTH;
        const int c = p - r * WIDTH;
        const int pidx = (r + 1) * PW + (c + 1);
#pragma unroll
        for (int mb = 0; mb < 4; ++mb)
#pragma unroll
            for (int rr = 0; rr < 4; ++rr) {
                int o = mb * 16 + hi * 4 + rr;
                float v = relu(fmaf(acc[nb][mb][rr], g[o] * BN_INV, bb[o]));
                ybase[(size_t)o * YPLANE + pidx] = f2bf(v);
            }
    }
}

// k2: cv[nt,k,p] = relu(bn22( (1/CR) * sum_ch y1*y2(shifted) )).  (round-5 proven)
__global__ __launch_bounds__(256) void k2_corr(const unsigned short* __restrict__ y,
                                               const float* __restrict__ g,
                                               const float* __restrict__ bb,
                                               float* __restrict__ cv) {
    int gt   = blockIdx.x * 256 + threadIdx.x;   // 0..100351
    int h    = gt & 3;                           // ch quarter
    int task = gt >> 2;                          // 0..25087
    int nt   = task / 392;                       // 392 = 56 rows * 7 cgroups
    int rm   = task - nt * 392;
    int r    = rm / 7;
    int cg   = rm - r * 7;
    int c0   = cg * 8;
    int nt2  = ((nt & (TT - 1)) < TT - 1) ? nt + 1 : nt;

    const unsigned short* y1 = y + ((size_t)nt * CR + h * 16) * YPLANE
                                 + (size_t)(r + 1) * PW + c0;
    const unsigned short* y2 = y + ((size_t)nt2 * CR + h * 16) * YPLANE
                                 + (size_t)r * PW + c0;

    float acc[9][8];
#pragma unroll
    for (int k = 0; k < 9; ++k)
#pragma unroll
        for (int px = 0; px < 8; ++px) acc[k][px] = 0.0f;

#pragma unroll 2
    for (int ch = 0; ch < 16; ++ch) {
        const unsigned short* p1 = y1 + (size_t)ch * YPLANE;
        ushort8 a8 = *(const ushort8*)p1;
        unsigned at = *(const unsigned*)(p1 + 8);
        float a[8];
#pragma unroll
        for (int j = 0; j < 7; ++j) a[j] = bf2f(a8[j + 1]);
        a[7] = bf2f((unsigned short)(at & 0xffffu));

        const unsigned short* p2 = y2 + (size_t)ch * YPLANE;
#pragma unroll
        for (int dy = 0; dy < 3; ++dy) {
            const unsigned short* pr = p2 + dy * PW;
            ushort8 b8 = *(const ushort8*)pr;
            unsigned bt = *(const unsigned*)(pr + 8);
            float w[10];
#pragma unroll
            for (int j = 0; j < 8; ++j) w[j] = bf2f(b8[j]);
            w[8] = bf2f((unsigned short)(bt & 0xffffu));
            w[9] = bf2f((unsigned short)(bt >> 16));
#pragma unroll
            for (int dx = 0; dx < 3; ++dx) {
                int k = dy * 3 + dx;
#pragma unroll
                for (int px = 0; px < 8; ++px)
                    acc[k][px] = fmaf(a[px], w[px + dx], acc[k][px]);
            }
        }
    }

    // reduce across the 4 ch-quarter lanes (xor 1, xor 2)
#pragma unroll
    for (int k = 0; k < 9; ++k)
#pragma unroll
        for (int px = 0; px < 8; ++px) {
            float v = acc[k][px];
            v += __shfl_xor(v, 1);
            v += __shfl_xor(v, 2);
            acc[k][px] = v;
        }

    if (h == 0) {
        float* cp = cv + (size_t)nt * 9 * HW + r * WIDTH + c0;
        const float rcr = 1.0f / CR;
#pragma unroll
        for (int k = 0; k < 9; ++k) {
            float sc = g[k] * BN_INV, bv = bb[k];
            f32x4 lo, hi;
            lo.x = relu(fmaf(acc[k][0] * rcr, sc, bv));
            lo.y = relu(fmaf(acc[k][1] * rcr, sc, bv));
            lo.z = relu(fmaf(acc[k][2] * rcr, sc, bv));
            lo.w = relu(fmaf(acc[k][3] * rcr, sc, bv));
            hi.x = relu(fmaf(acc[k][4] * rcr, sc, bv));
            hi.y = relu(fmaf(acc[k][5] * rcr, sc, bv));
            hi.z = relu(fmaf(acc[k][6] * rcr, sc, bv));
            hi.w = relu(fmaf(acc[k][7] * rcr, sc, bv));
            *(f32x4*)(cp + (size_t)k * HW)     = lo;
            *(f32x4*)(cp + (size_t)k * HW + 4) = hi;
        }
    }
}

// k3: out = relu(bn23(conv22(cv)) + x).  (round-5 proven)
__global__ __launch_bounds__(256) void k3_conv22(const float* __restrict__ cv,
                                                 const float* __restrict__ w2,
                                                 const float* __restrict__ g,
                                                 const float* __restrict__ bb,
                                                 const float* __restrict__ x,
                                                 float* __restrict__ out) {
    int gt = blockIdx.x * 256 + threadIdx.x;   // 0..100351
    int nt = gt / 1568;                        // 1568 = 3136/2
    int p2 = (gt - nt * 1568) * 2;

    const float* cp = cv + (size_t)nt * 9 * HW + p2;
    float cvx[9], cvy[9];
#pragma unroll
    for (int k = 0; k < 9; ++k) {
        f32x2 v = *(const f32x2*)(cp + (size_t)k * HW);
        cvx[k] = v.x; cvy[k] = v.y;
    }

    const float* xp = x   + (size_t)nt * (C * HW) + p2;
    float*       op = out + (size_t)nt * (C * HW) + p2;

#pragma unroll 8
    for (int o = 0; o < C; ++o) {
        const float* wr = w2 + o * 9;
        f32x2 xr = *(const f32x2*)(xp + (size_t)o * HW);
        float sx = 0.0f, sy = 0.0f;
#pragma unroll
        for (int k = 0; k < 9; ++k) {
            float wv = wr[k];
            sx = fmaf(wv, cvx[k], sx);
            sy = fmaf(wv, cvy[k], sy);
        }
        float sc = g[o] * BN_INV, bv = bb[o];
        f32x2 rv;
        rv.x = relu(fmaf(sx, sc, bv) + xr.x);
        rv.y = relu(fmaf(sy, sc, bv) + xr.y);
        *(f32x2*)(op + (size_t)o * HW) = rv;
    }
}

extern "C" void kernel_launch(void* const* d_in, const int* in_sizes, int n_in,
                              void* d_out, int out_size, void* d_ws, size_t ws_size,
                              hipStream_t stream) {
    const float* x   = (const float*)d_in[0];
    const float* w21 = (const float*)d_in[1];
    const float* g21 = (const float*)d_in[2];
    const float* b21 = (const float*)d_in[3];
    const float* g22 = (const float*)d_in[4];
    const float* b22 = (const float*)d_in[5];
    const float* w22 = (const float*)d_in[6];
    const float* g23 = (const float*)d_in[7];
    const float* b23 = (const float*)d_in[8];
    float* out = (float*)d_out;

    // ws: y bf16 padded (30.4MB) | cv fp32 (7.2MB) | wbf (32KB)
    unsigned short* yb  = (unsigned short*)d_ws;
    float*          cvb = (float*)((char*)d_ws + YBYTES);
    unsigned short* wbf = (unsigned short*)((char*)d_ws + YBYTES + CVBYTES);

    k0_cvt_w     <<<64,  256, 0, stream>>>(w21, wbf);
    k1_mfma<256> <<<832, 256, 0, stream>>>(x, wbf, g21, b21, yb);  // 768 tiles + 64 halo
    k1_mfma<64>  <<<64,  256, 0, stream>>>(x, wbf, g21, b21, yb);  // px 3072..3135
    k2_corr      <<<392, 256, 0, stream>>>(yb, g22, b22, cvb);
    k3_conv22    <<<392, 256, 0, stream>>>(cvb, w22, g23, b23, x, out);
}